// Round 8
// baseline (177.665 us; speedup 1.0000x reference)
//
#include <hip/hip_runtime.h>
#include <float.h>

// Quantize: z [8,4096,512] f32, embed_w [512,128] f32, GROUPS=4
// flat = z.reshape(131072,128); dist to 512 codes; argmin; gather; MSE scalar.
// d_out (f32): z_q_st [16777216], diff [1], ind [131072] (as float).
//
// Round-8 structure: NO codebook LDS. fp16 codebook (128 KB, L2-resident)
// pre-converted to a tile-major layout so each wave B-tile read is one
// contiguous coalesced 1 KB transaction, software-pipelined 2 tiles deep.
// 256-thread blocks (4 waves x 32 rows), ~1.5 KB LDS, zero barriers until
// the final per-block diff reduce. Scores a = x16.w16 - 0.5*||w||^2 via MFMA;
// rows with top-2 margin < TAU_A re-solved exactly in fp64 => exact indices.

typedef _Float16 half8 __attribute__((ext_vector_type(8)));
typedef __attribute__((ext_vector_type(4))) float f32x4;

constexpr int Dn = 128;
constexpr int K  = 512;
constexpr long long Mrows = 131072;
constexpr int RPW   = 32;                    // rows per wave
constexpr int WAVES = 4;                     // waves per block (256 threads)
constexpr int RPB   = RPW * WAVES;           // 128 rows per block
constexpr int NBLK  = (int)(Mrows / RPB);    // 1024
constexpr float TAU_A = 0.05f;               // score-margin for fp64 re-solve

constexpr size_t ZQ_SIZE  = (size_t)Mrows * Dn;
constexpr size_t DIFF_OFF = ZQ_SIZE;
constexpr size_t IND_OFF  = ZQ_SIZE + 1;

// W -> fp16, tile-major: for tile t (16 codes), k-slot ks (0..3):
// 1 KB block at (t*4+ks)*1024 holding lane data at lm*64 + lg*16
// (code = t*16+lm, dims (ks*4+lg)*8 .. +8). One wave B-read = contiguous 1KB.
// Also computes wn2[code] = -0.5*||w||^2 (fp64 accumulate).
__global__ void prep_kernel(const float* __restrict__ W,
                            unsigned short* __restrict__ Wp2,
                            float* __restrict__ wn2) {
    int t = blockIdx.x * 256 + threadIdx.x;  // 0..8191: code*16 + g
    int code = t >> 4;
    int g    = t & 15;
    const float* src = W + (size_t)code * Dn + g * 8;
    float4 a = *(const float4*)src;
    float4 b = *(const float4*)(src + 4);
    float vv[8] = {a.x, a.y, a.z, a.w, b.x, b.y, b.z, b.w};
    half8 hv;
    float s2 = 0.f;
    #pragma unroll
    for (int j = 0; j < 8; ++j) {
        hv[j] = (_Float16)vv[j];
        s2 += vv[j] * vv[j];
    }
    int ks = g >> 2, lg = g & 3;
    size_t byte = ((size_t)((code >> 4) * 4 + ks)) * 1024 + (code & 15) * 64 + lg * 16;
    *(half8*)((char*)Wp2 + byte) = hv;
    // reduce s2 over the 16 threads of this code (consecutive lanes)
    s2 += __shfl_xor(s2, 1);
    s2 += __shfl_xor(s2, 2);
    s2 += __shfl_xor(s2, 4);
    s2 += __shfl_xor(s2, 8);
    if (g == 0) wn2[code] = -0.5f * s2;
}

__global__ __launch_bounds__(256, 4) void vq_main(
        const float* __restrict__ Z, const float* __restrict__ W,
        const unsigned short* __restrict__ Wp2, const float* __restrict__ wn2,
        float* __restrict__ out, double* __restrict__ diffsum) {
    __shared__ float xn_s[RPB];
    __shared__ int   sIdx[RPB];
    __shared__ int   sFlag[RPB];
    __shared__ float wpart[WAVES];

    const int tid  = threadIdx.x;
    const int w    = tid >> 6;
    const int lane = tid & 63;
    const int lm   = lane & 15;        // A row / B col within 16-tile
    const int lg   = lane >> 4;        // k-block (0..3)
    const size_t row0 = (size_t)blockIdx.x * RPB;

    // ---- X fragments (fp16) + exact row norms, in registers ----
    half8 ah[2][4];                     // [16-row tile][ks]
    #pragma unroll
    for (int r = 0; r < 2; ++r) {
        const size_t grow = row0 + (size_t)w * RPW + r * 16 + lm;
        float s2 = 0.f;
        #pragma unroll
        for (int ks = 0; ks < 4; ++ks) {
            const float* xp = Z + grow * Dn + ks * 32 + lg * 8;
            float4 x0 = *(const float4*)xp;
            float4 x1 = *(const float4*)(xp + 4);
            float xv[8] = {x0.x, x0.y, x0.z, x0.w, x1.x, x1.y, x1.z, x1.w};
            #pragma unroll
            for (int j = 0; j < 8; ++j) {
                ah[r][ks][j] = (_Float16)xv[j];
                s2 += xv[j] * xv[j];
            }
        }
        s2 += __shfl_xor(s2, 16);
        s2 += __shfl_xor(s2, 32);      // full ||x||^2 for row grow
        if (lg == 0) xn_s[w * RPW + r * 16 + lm] = s2;
    }

    float m1[2][4], m2[2][4];
    int   i1[2][4];
    #pragma unroll
    for (int r = 0; r < 2; ++r)
        #pragma unroll
        for (int j = 0; j < 4; ++j) { m1[r][j] = -FLT_MAX; m2[r][j] = -FLT_MAX; i1[r][j] = 0; }

    // ---- main scan: B tiles streamed from L2, 2-tile software pipeline ----
    const char* WP = (const char*)Wp2;
    const int lofs = lm * 64 + lg * 16;

    half8 bhA[4], bhB[4];
    float cinA, cinB;

    #define LOADB(BH, CIN, T) do {                                   \
        const char* p_ = WP + (size_t)(T) * 4096 + lofs;             \
        BH[0] = *(const half8*)(p_);                                 \
        BH[1] = *(const half8*)(p_ + 1024);                          \
        BH[2] = *(const half8*)(p_ + 2048);                          \
        BH[3] = *(const half8*)(p_ + 3072);                          \
        CIN = wn2[(T) * 16 + lm];                                    \
    } while (0)

    #define COMP(BH, CIN, T) do {                                    \
        f32x4 acc0 = (f32x4){CIN, CIN, CIN, CIN};                    \
        f32x4 acc1 = acc0;                                           \
        _Pragma("unroll")                                            \
        for (int ks = 0; ks < 4; ++ks) {                             \
            acc0 = __builtin_amdgcn_mfma_f32_16x16x32_f16(ah[0][ks], BH[ks], acc0, 0, 0, 0); \
            acc1 = __builtin_amdgcn_mfma_f32_16x16x32_f16(ah[1][ks], BH[ks], acc1, 0, 0, 0); \
        }                                                            \
        const int code_ = (T) * 16 + lm;                             \
        _Pragma("unroll")                                            \
        for (int j = 0; j < 4; ++j) {                                \
            float a0 = acc0[j];                                      \
            m2[0][j] = __builtin_amdgcn_fmed3f(a0, m1[0][j], m2[0][j]); \
            bool g0 = a0 > m1[0][j];                                 \
            m1[0][j] = fmaxf(m1[0][j], a0);                          \
            i1[0][j] = g0 ? code_ : i1[0][j];                        \
            float a1 = acc1[j];                                      \
            m2[1][j] = __builtin_amdgcn_fmed3f(a1, m1[1][j], m2[1][j]); \
            bool g1 = a1 > m1[1][j];                                 \
            m1[1][j] = fmaxf(m1[1][j], a1);                          \
            i1[1][j] = g1 ? code_ : i1[1][j];                        \
        }                                                            \
    } while (0)

    LOADB(bhA, cinA, 0);
    LOADB(bhB, cinB, 1);
    #pragma unroll 2
    for (int t = 0; t < 32; t += 2) {
        COMP(bhA, cinA, t);
        if (t + 2 < 32) LOADB(bhA, cinA, t + 2);
        COMP(bhB, cinB, t + 1);
        if (t + 3 < 32) LOADB(bhB, cinB, t + 3);
    }
    #undef LOADB
    #undef COMP

    // ---- reduce (m1, idx, m2) across the 16 col-lanes (wave-local) ----
    #pragma unroll
    for (int sft = 1; sft < 16; sft <<= 1) {
        #pragma unroll
        for (int r = 0; r < 2; ++r) {
            #pragma unroll
            for (int j = 0; j < 4; ++j) {
                float o1 = __shfl_xor(m1[r][j], sft);
                float o2 = __shfl_xor(m2[r][j], sft);
                int   oi = __shfl_xor(i1[r][j], sft);
                if (o1 > m1[r][j] || (o1 == m1[r][j] && oi < i1[r][j])) {
                    m2[r][j] = fmaxf(m1[r][j], o2);
                    m1[r][j] = o1;
                    i1[r][j] = oi;
                } else {
                    m2[r][j] = fmaxf(m2[r][j], o1);
                }
            }
        }
    }

    float psum = 0.f;
    if (lm == 0) {
        #pragma unroll
        for (int r = 0; r < 2; ++r) {
            #pragma unroll
            for (int j = 0; j < 4; ++j) {
                const int row = w * RPW + r * 16 + lg * 4 + j;   // C row = lg*4 + reg
                sIdx[row]  = i1[r][j];
                sFlag[row] = (m1[r][j] - m2[r][j] < TAU_A) ? 1 : 0;
                psum += xn_s[row] - 2.f * m1[r][j];              // dist^2 = ||x||^2 - 2a
            }
        }
    }
    // wave-local LDS (same-wave write->read ordering; no barrier needed)

    // ---- fp64 exact refinement of this wave's near-tie rows (rare) ----
    {
        const int cg    = lane >> 3;           // code subgroup 0..7
        const int dbase = (lane & 7) * 16;     // 16-dim slice per lane
        unsigned long long fl = __ballot(lane < 32 && sFlag[w * RPW + (lane & 31)] != 0);
        while (fl) {
            const int rr = __ffsll(fl) - 1;    // wave-local row 0..31
            fl &= fl - 1;
            const float* xp = Z + (row0 + w * RPW + rr) * Dn + dbase;
            double xd[16];
            #pragma unroll
            for (int q = 0; q < 16; q += 4) {
                float4 v = *(const float4*)(xp + q);
                xd[q] = v.x; xd[q+1] = v.y; xd[q+2] = v.z; xd[q+3] = v.w;
            }
            double best = 1e300; int bi = 0;
            for (int cb = 0; cb < 64; ++cb) {
                const int c = cb * 8 + cg;
                const float* wp = W + (size_t)c * Dn + dbase;
                double s = 0.0;
                #pragma unroll
                for (int q = 0; q < 16; q += 4) {
                    float4 wv = *(const float4*)(wp + q);
                    double d0 = xd[q]   - (double)wv.x;
                    double d1 = xd[q+1] - (double)wv.y;
                    double d2 = xd[q+2] - (double)wv.z;
                    double d3 = xd[q+3] - (double)wv.w;
                    s += d0 * d0 + d1 * d1 + d2 * d2 + d3 * d3;
                }
                s += __shfl_xor(s, 1);
                s += __shfl_xor(s, 2);
                s += __shfl_xor(s, 4);         // all 8 lanes of group hold s(c)
                if (s < best) { best = s; bi = c; }   // ascending c => min-idx tiebreak
            }
            #pragma unroll
            for (int sft = 8; sft < 64; sft <<= 1) {
                double ob = __shfl_xor(best, sft);
                int    ok = __shfl_xor(bi, sft);
                if (ob < best || (ob == best && ok < bi)) { best = ob; bi = ok; }
            }
            if (lane == 0) sIdx[w * RPW + rr] = bi;
        }
    }

    // ---- per-wave epilogue: gather W[ind], store z_q_st, ind ----
    #pragma unroll
    for (int it = 0; it < 16; ++it) {
        int f4i = lane + it * 64;              // 0..1023
        int rl  = f4i >> 5, cq = f4i & 31;     // 32 rows x 32 float4
        int ind = sIdx[w * RPW + rl];
        float4 wv = ((const float4*)(W + (size_t)ind * Dn))[cq];
        ((float4*)(out + (row0 + w * RPW + rl) * Dn))[cq] = wv;
    }
    if (lane < RPW)
        out[IND_OFF + row0 + w * RPW + lane] = (float)sIdx[w * RPW + lane];

    // ---- diff partial: one atomic per block ----
    #pragma unroll
    for (int sft = 1; sft < 64; sft <<= 1) psum += __shfl_xor(psum, sft);
    if (lane == 0) wpart[w] = psum;
    __syncthreads();                           // the block's ONLY barrier
    if (tid == 0) {
        double t = 0.0;
        #pragma unroll
        for (int i = 0; i < WAVES; ++i) t += (double)wpart[i];
        atomicAdd(diffsum, t);
    }
}

__global__ void diff_kernel(const double* __restrict__ diffsum, float* __restrict__ out) {
    if (threadIdx.x == 0 && blockIdx.x == 0) {
        // KLD_SCALE * (COMMITMENT_COST + 1) * mean = 12.5 * mean
        out[DIFF_OFF] = (float)(12.5 * diffsum[0] / (double)ZQ_SIZE);
    }
}

extern "C" void kernel_launch(void* const* d_in, const int* in_sizes, int n_in,
                              void* d_out, int out_size, void* d_ws, size_t ws_size,
                              hipStream_t stream) {
    (void)in_sizes; (void)n_in; (void)out_size; (void)ws_size;
    const float* Z = (const float*)d_in[0];
    const float* W = (const float*)d_in[1];
    float* out = (float*)d_out;
    // ws layout: [0,8) diffsum double; [16,2064) wn2 f32[512]; [4096, +128KB) Wp2
    double* diffsum = (double*)d_ws;
    float* wn2 = (float*)((char*)d_ws + 16);
    unsigned short* Wp2 = (unsigned short*)((char*)d_ws + 4096);

    hipMemsetAsync(d_ws, 0, 16, stream);
    prep_kernel<<<32, 256, 0, stream>>>(W, Wp2, wn2);
    vq_main<<<NBLK, 256, 0, stream>>>(Z, W, Wp2, wn2, out, diffsum);
    diff_kernel<<<1, 64, 0, stream>>>(diffsum, out);
}

// Round 9
// 113.757 us; speedup vs baseline: 1.5618x; 1.5618x over previous
//
#include <hip/hip_runtime.h>
#include <float.h>

// Quantize: z [8,4096,512] f32, embed_w [512,128] f32, GROUPS=4
// flat = z.reshape(131072,128); dist to 512 codes; argmin; gather; MSE scalar.
// d_out (f32): z_q_st [16777216], diff [1], ind [131072] (as float).
//
// r9 = r6 champion + block-distributed exact refinement:
//  - fp16-hi codebook (128 KB) DMA'd once into LDS (pre-swizzled Wp), 1 barrier
//  - 16 waves x 32 rows scan all 512 codes via MFMA, per-wave staggered
//  - rows with top-2 score margin < TAU_A pushed to an LDS worklist and
//    re-solved EXACTLY (fp64 dot + fp64 ||w||^2) by all 16 waves in parallel
//    => exact argmin indices, no per-wave straggler

typedef _Float16 half8 __attribute__((ext_vector_type(8)));
typedef __attribute__((ext_vector_type(4))) float f32x4;

constexpr int Dn = 128;
constexpr int K  = 512;
constexpr long long Mrows = 131072;
constexpr int RPW   = 32;                    // rows per wave
constexpr int WAVES = 16;                    // waves per block (1024 threads)
constexpr int RPB   = RPW * WAVES;           // 512 rows per block
constexpr int NBLK  = (int)(Mrows / RPB);    // 256
constexpr float TAU_A = 0.05f;               // score-margin for exact re-solve

constexpr size_t ZQ_SIZE  = (size_t)Mrows * Dn;
constexpr size_t DIFF_OFF = ZQ_SIZE;
constexpr size_t IND_OFF  = ZQ_SIZE + 1;

__device__ inline void gload_lds16(const void* g, void* l) {
    __builtin_amdgcn_global_load_lds(
        (const __attribute__((address_space(1))) unsigned int*)g,
        (__attribute__((address_space(3))) unsigned int*)l,
        16, 0, 0);
}

// W -> fp16 hi, XOR-swizzled granule order (granule g of code stored at slot
// g ^ (code&7)); also wn2 = -0.5*||w||^2 (f32) and wn64 = ||w||^2 (f64).
__global__ void prep_kernel(const float* __restrict__ W,
                            unsigned short* __restrict__ Wp,
                            float* __restrict__ wn2,
                            double* __restrict__ wn64) {
    int t = blockIdx.x * 256 + threadIdx.x;  // 0..8191 (512 codes * 16 granules)
    int code = t >> 4;
    int g    = t & 15;
    const float* src = W + (size_t)code * Dn + g * 8;
    float4 a = *(const float4*)src;
    float4 b = *(const float4*)(src + 4);
    float vv[8] = {a.x, a.y, a.z, a.w, b.x, b.y, b.z, b.w};
    half8 hv;
    double s2 = 0.0;
    #pragma unroll
    for (int j = 0; j < 8; ++j) {
        hv[j] = (_Float16)vv[j];
        s2 += (double)vv[j] * (double)vv[j];
    }
    *(half8*)((char*)Wp + (size_t)code * 256 + ((g ^ (code & 7)) << 4)) = hv;
    s2 += __shfl_xor(s2, 1);
    s2 += __shfl_xor(s2, 2);
    s2 += __shfl_xor(s2, 4);
    s2 += __shfl_xor(s2, 8);
    if (g == 0) {
        wn2[code]  = (float)(-0.5 * s2);
        wn64[code] = s2;
    }
}

__global__ __launch_bounds__(1024, 4) void vq_main(
        const float* __restrict__ Z, const float* __restrict__ W,
        const unsigned short* __restrict__ Wp, const float* __restrict__ wn2,
        const double* __restrict__ wn64,
        float* __restrict__ out, double* __restrict__ diffsum) {
    __shared__ __align__(16) char Wlds[131072];   // full codebook, fp16 hi, swizzled
    __shared__ float wn2_s[K];
    __shared__ float xn_s[RPB];
    __shared__ int   sIdx[RPB];
    __shared__ int   flagList[RPB];
    __shared__ int   flagN;
    __shared__ float wpart[WAVES];

    const int tid  = threadIdx.x;
    const int w    = tid >> 6;
    const int lane = tid & 63;
    const int lm   = lane & 15;        // A row / B col within 16-tile
    const int lg   = lane >> 4;        // k-block (0..3)
    const size_t row0 = (size_t)blockIdx.x * RPB;

    if (tid == 0) flagN = 0;

    // ---- codebook DMA: 128 KB once, linear dest (pre-swizzled src) ----
    {
        const char* gsrc = (const char*)Wp;
        #pragma unroll
        for (int it = 0; it < 8; ++it) {
            const int gbase = it * 1024 + w * 64;            // wave-uniform base
            gload_lds16(gsrc + (size_t)(gbase + lane) * 16, Wlds + (size_t)gbase * 16);
        }
    }
    if (tid < K) wn2_s[tid] = wn2[tid];

    // ---- X fragments (fp16) + exact row norms (overlap the DMA) ----
    half8 ah[2][4];                     // [16-row tile][ks]
    #pragma unroll
    for (int r = 0; r < 2; ++r) {
        const size_t grow = row0 + (size_t)w * RPW + r * 16 + lm;
        float s2 = 0.f;
        #pragma unroll
        for (int ks = 0; ks < 4; ++ks) {
            const float* xp = Z + grow * Dn + ks * 32 + lg * 8;
            float4 x0 = *(const float4*)xp;
            float4 x1 = *(const float4*)(xp + 4);
            float xv[8] = {x0.x, x0.y, x0.z, x0.w, x1.x, x1.y, x1.z, x1.w};
            #pragma unroll
            for (int j = 0; j < 8; ++j) {
                ah[r][ks][j] = (_Float16)xv[j];
                s2 += xv[j] * xv[j];
            }
        }
        s2 += __shfl_xor(s2, 16);
        s2 += __shfl_xor(s2, 32);      // full ||x||^2 for row grow
        if (lg == 0) xn_s[w * RPW + r * 16 + lm] = s2;
    }

    float m1[2][4], m2[2][4];
    int   i1[2][4];
    #pragma unroll
    for (int r = 0; r < 2; ++r)
        #pragma unroll
        for (int j = 0; j < 4; ++j) { m1[r][j] = -FLT_MAX; m2[r][j] = -FLT_MAX; i1[r][j] = 0; }

    asm volatile("s_waitcnt vmcnt(0)" ::: "memory");
    __syncthreads();                   // B1: codebook + wn2 + flagN=0 visible

    // ---- main scan: 32 B-tiles, per-wave staggered start, no syncs ----
    const int t0 = (w * 2) & 31;
    #pragma unroll 2
    for (int ti = 0; ti < 32; ++ti) {
        const int t = (ti + t0) & 31;
        const int code = t * 16 + lm;
        const float cinit = wn2_s[code];
        half8 bh[4];
        #pragma unroll
        for (int ks = 0; ks < 4; ++ks) {
            const int off = code * 256 + ((((ks << 2) + lg) ^ (code & 7)) << 4);
            bh[ks] = *(const half8*)(Wlds + off);
        }
        f32x4 acc[2];
        #pragma unroll
        for (int r = 0; r < 2; ++r) acc[r] = (f32x4){cinit, cinit, cinit, cinit};
        #pragma unroll
        for (int ks = 0; ks < 4; ++ks) {
            #pragma unroll
            for (int r = 0; r < 2; ++r)
                acc[r] = __builtin_amdgcn_mfma_f32_16x16x32_f16(ah[r][ks], bh[ks], acc[r], 0, 0, 0);
        }
        #pragma unroll
        for (int r = 0; r < 2; ++r) {
            #pragma unroll
            for (int j = 0; j < 4; ++j) {
                const float a = acc[r][j];
                m2[r][j] = __builtin_amdgcn_fmed3f(a, m1[r][j], m2[r][j]);
                const bool gt = a > m1[r][j];
                m1[r][j] = fmaxf(m1[r][j], a);
                i1[r][j] = gt ? code : i1[r][j];
            }
        }
    }

    // ---- reduce (m1, idx, m2) across the 16 col-lanes (wave-local) ----
    #pragma unroll
    for (int sft = 1; sft < 16; sft <<= 1) {
        #pragma unroll
        for (int r = 0; r < 2; ++r) {
            #pragma unroll
            for (int j = 0; j < 4; ++j) {
                float o1 = __shfl_xor(m1[r][j], sft);
                float o2 = __shfl_xor(m2[r][j], sft);
                int   oi = __shfl_xor(i1[r][j], sft);
                if (o1 > m1[r][j] || (o1 == m1[r][j] && oi < i1[r][j])) {
                    m2[r][j] = fmaxf(m1[r][j], o2);
                    m1[r][j] = o1;
                    i1[r][j] = oi;
                } else {
                    m2[r][j] = fmaxf(m2[r][j], o1);
                }
            }
        }
    }

    float psum = 0.f;
    if (lm == 0) {
        #pragma unroll
        for (int r = 0; r < 2; ++r) {
            #pragma unroll
            for (int j = 0; j < 4; ++j) {
                const int row = w * RPW + r * 16 + lg * 4 + j;   // C row = lg*4 + reg
                sIdx[row] = i1[r][j];
                psum += xn_s[row] - 2.f * m1[r][j];              // dist^2 = ||x||^2 - 2a
                if (m1[r][j] - m2[r][j] < TAU_A) {
                    int pos = atomicAdd(&flagN, 1);
                    flagList[pos] = row;
                }
            }
        }
    }
    __syncthreads();                   // B2: sIdx + worklist complete

    // ---- exact refinement, block-distributed over the worklist ----
    {
        const int nf = flagN;
        const int cg    = lane >> 3;           // code subgroup 0..7
        const int dbase = (lane & 7) * 16;     // 16-dim slice per lane
        for (int fi = w; fi < nf; fi += WAVES) {
            const int rr = flagList[fi];
            const float* xp = Z + (row0 + rr) * Dn + dbase;
            double xd[16];
            #pragma unroll
            for (int q = 0; q < 16; q += 4) {
                float4 v = *(const float4*)(xp + q);
                xd[q] = v.x; xd[q+1] = v.y; xd[q+2] = v.z; xd[q+3] = v.w;
            }
            double best = 1e300; int bi = 0;
            for (int cb = 0; cb < 64; ++cb) {
                const int c = cb * 8 + cg;
                const float* wp = W + (size_t)c * Dn + dbase;
                double s = 0.0;
                #pragma unroll
                for (int q = 0; q < 16; q += 4) {
                    float4 wv = *(const float4*)(wp + q);
                    s += xd[q]   * (double)wv.x;
                    s += xd[q+1] * (double)wv.y;
                    s += xd[q+2] * (double)wv.z;
                    s += xd[q+3] * (double)wv.w;
                }
                s += __shfl_xor(s, 1);
                s += __shfl_xor(s, 2);
                s += __shfl_xor(s, 4);         // all 8 lanes of group hold dot(c)
                const double sc = wn64[c] - 2.0 * s;   // dist^2 - ||x||^2 (exact order)
                if (sc < best) { best = sc; bi = c; } // ascending c => min-idx tiebreak
            }
            #pragma unroll
            for (int sft = 8; sft < 64; sft <<= 1) {
                double ob = __shfl_xor(best, sft);
                int    ok = __shfl_xor(bi, sft);
                if (ob < best || (ob == best && ok < bi)) { best = ob; bi = ok; }
            }
            if (lane == 0) sIdx[rr] = bi;
        }
    }
    __syncthreads();                   // B3: refined sIdx visible to all waves

    // ---- epilogue: gather W[ind], store z_q_st, ind, diff ----
    #pragma unroll
    for (int it = 0; it < 16; ++it) {
        int f4i = lane + it * 64;              // 0..1023
        int rl  = f4i >> 5, cq = f4i & 31;     // 32 rows x 32 float4
        int ind = sIdx[w * RPW + rl];
        float4 wv = ((const float4*)(W + (size_t)ind * Dn))[cq];
        ((float4*)(out + (row0 + w * RPW + rl) * Dn))[cq] = wv;
    }
    if (lane < RPW)
        out[IND_OFF + row0 + w * RPW + lane] = (float)sIdx[w * RPW + lane];

    #pragma unroll
    for (int sft = 1; sft < 64; sft <<= 1) psum += __shfl_xor(psum, sft);
    if (lane == 0) wpart[w] = psum;
    __syncthreads();
    if (tid == 0) {
        double t = 0.0;
        #pragma unroll
        for (int i = 0; i < WAVES; ++i) t += (double)wpart[i];
        atomicAdd(diffsum, t);
    }
}

__global__ void diff_kernel(const double* __restrict__ diffsum, float* __restrict__ out) {
    if (threadIdx.x == 0 && blockIdx.x == 0) {
        // KLD_SCALE * (COMMITMENT_COST + 1) * mean = 12.5 * mean
        out[DIFF_OFF] = (float)(12.5 * diffsum[0] / (double)ZQ_SIZE);
    }
}

extern "C" void kernel_launch(void* const* d_in, const int* in_sizes, int n_in,
                              void* d_out, int out_size, void* d_ws, size_t ws_size,
                              hipStream_t stream) {
    (void)in_sizes; (void)n_in; (void)out_size; (void)ws_size;
    const float* Z = (const float*)d_in[0];
    const float* W = (const float*)d_in[1];
    float* out = (float*)d_out;
    // ws: [0,8) diffsum; [64,2112) wn2 f32[512]; [2112,6208) wn64 f64[512];
    //     [8192, +128KB) Wp fp16 swizzled
    double* diffsum = (double*)d_ws;
    float*  wn2  = (float*)((char*)d_ws + 64);
    double* wn64 = (double*)((char*)d_ws + 2112);
    unsigned short* Wp = (unsigned short*)((char*)d_ws + 8192);

    hipMemsetAsync(d_ws, 0, 16, stream);
    prep_kernel<<<32, 256, 0, stream>>>(W, Wp, wn2, wn64);
    vq_main<<<NBLK, 1024, 0, stream>>>(Z, W, Wp, wn2, wn64, out, diffsum);
    diff_kernel<<<1, 64, 0, stream>>>(diffsum, out);
}

// Round 10
// 113.126 us; speedup vs baseline: 1.5705x; 1.0056x over previous
//
#include <hip/hip_runtime.h>
#include <float.h>

// Quantize: z [8,4096,512] f32, embed_w [512,128] f32, GROUPS=4
// flat = z.reshape(131072,128); dist to 512 codes; argmin; gather; MSE scalar.
// d_out (f32): z_q_st [16777216], diff [1], ind [131072] (as float).
//
// r10 = r6/r9 numerics with 2-blocks-per-CU phase overlap:
//  - codebook scanned in TWO passes of 256 codes; the 64 KB fp16 slice is
//    DMA'd into LDS per pass (pre-swizzled Wp, linear global_load_lds)
//  - 8 waves x 32 rows per block (512 blocks) -> ~70 KB LDS -> 2 blocks/CU,
//    so one block's Z-load/refine/store overlaps the sibling's MFMA scan
//  - rows with top-2 score margin < TAU_A re-solved EXACTLY in fp64
//    (fp64 dot + fp64 ||w||^2, block-distributed worklist) => exact indices

typedef _Float16 half8 __attribute__((ext_vector_type(8)));
typedef __attribute__((ext_vector_type(4))) float f32x4;

constexpr int Dn = 128;
constexpr int K  = 512;
constexpr long long Mrows = 131072;
constexpr int RPW   = 32;                    // rows per wave
constexpr int WAVES = 8;                     // waves per block (512 threads)
constexpr int RPB   = RPW * WAVES;           // 256 rows per block
constexpr int NBLK  = (int)(Mrows / RPB);    // 512
constexpr int KHALF = 256;                   // codes per pass (64 KB fp16)
constexpr float TAU_A = 0.05f;               // score-margin for exact re-solve

constexpr size_t ZQ_SIZE  = (size_t)Mrows * Dn;
constexpr size_t DIFF_OFF = ZQ_SIZE;
constexpr size_t IND_OFF  = ZQ_SIZE + 1;

__device__ inline void gload_lds16(const void* g, void* l) {
    __builtin_amdgcn_global_load_lds(
        (const __attribute__((address_space(1))) unsigned int*)g,
        (__attribute__((address_space(3))) unsigned int*)l,
        16, 0, 0);
}

// W -> fp16 hi, XOR-swizzled granule order (granule g of code stored at slot
// g ^ (code&7)); also wn2 = -0.5*||w||^2 (f32) and wn64 = ||w||^2 (f64).
__global__ void prep_kernel(const float* __restrict__ W,
                            unsigned short* __restrict__ Wp,
                            float* __restrict__ wn2,
                            double* __restrict__ wn64) {
    int t = blockIdx.x * 256 + threadIdx.x;  // 0..8191 (512 codes * 16 granules)
    int code = t >> 4;
    int g    = t & 15;
    const float* src = W + (size_t)code * Dn + g * 8;
    float4 a = *(const float4*)src;
    float4 b = *(const float4*)(src + 4);
    float vv[8] = {a.x, a.y, a.z, a.w, b.x, b.y, b.z, b.w};
    half8 hv;
    double s2 = 0.0;
    #pragma unroll
    for (int j = 0; j < 8; ++j) {
        hv[j] = (_Float16)vv[j];
        s2 += (double)vv[j] * (double)vv[j];
    }
    *(half8*)((char*)Wp + (size_t)code * 256 + ((g ^ (code & 7)) << 4)) = hv;
    s2 += __shfl_xor(s2, 1);
    s2 += __shfl_xor(s2, 2);
    s2 += __shfl_xor(s2, 4);
    s2 += __shfl_xor(s2, 8);
    if (g == 0) {
        wn2[code]  = (float)(-0.5 * s2);
        wn64[code] = s2;
    }
}

__global__ __launch_bounds__(512, 4) void vq_main(
        const float* __restrict__ Z, const float* __restrict__ W,
        const unsigned short* __restrict__ Wp, const float* __restrict__ wn2,
        const double* __restrict__ wn64,
        float* __restrict__ out, double* __restrict__ diffsum) {
    __shared__ __align__(16) char Wbuf[KHALF * 256];   // 64 KB: half codebook
    __shared__ float wn2_s[K];
    __shared__ float xn_s[RPB];
    __shared__ int   sIdx[RPB];
    __shared__ int   flagList[RPB];
    __shared__ int   flagN;
    __shared__ float wpart[WAVES];

    const int tid  = threadIdx.x;
    const int w    = tid >> 6;
    const int lane = tid & 63;
    const int lm   = lane & 15;        // A row / B col within 16-tile
    const int lg   = lane >> 4;        // k-block (0..3)
    const size_t row0 = (size_t)blockIdx.x * RPB;

    if (tid == 0) flagN = 0;

    // ---- stage: DMA one 64 KB codebook half into LDS (linear dest) ----
    auto stage = [&](int p) {
        const char* gsrc = (const char*)Wp + (size_t)p * (KHALF * 256);
        #pragma unroll
        for (int it = 0; it < 8; ++it) {
            const int gbase = it * 512 + w * 64;             // wave-uniform base
            gload_lds16(gsrc + (size_t)(gbase + lane) * 16, Wbuf + (size_t)gbase * 16);
        }
    };
    stage(0);                           // issue pass-0 DMA first

    // ---- X fragments (fp16) + exact row norms (overlap the DMA) ----
    half8 ah[2][4];                     // [16-row tile][ks]
    #pragma unroll
    for (int r = 0; r < 2; ++r) {
        const size_t grow = row0 + (size_t)w * RPW + r * 16 + lm;
        float s2 = 0.f;
        #pragma unroll
        for (int ks = 0; ks < 4; ++ks) {
            const float* xp = Z + grow * Dn + ks * 32 + lg * 8;
            float4 x0 = *(const float4*)xp;
            float4 x1 = *(const float4*)(xp + 4);
            float xv[8] = {x0.x, x0.y, x0.z, x0.w, x1.x, x1.y, x1.z, x1.w};
            #pragma unroll
            for (int j = 0; j < 8; ++j) {
                ah[r][ks][j] = (_Float16)xv[j];
                s2 += xv[j] * xv[j];
            }
        }
        s2 += __shfl_xor(s2, 16);
        s2 += __shfl_xor(s2, 32);      // full ||x||^2 for row grow
        if (lg == 0) xn_s[w * RPW + r * 16 + lm] = s2;
    }
    if (tid < K) wn2_s[tid] = wn2[tid];   // 512 threads = K

    float m1[2][4], m2[2][4];
    int   i1[2][4];
    #pragma unroll
    for (int r = 0; r < 2; ++r)
        #pragma unroll
        for (int j = 0; j < 4; ++j) { m1[r][j] = -FLT_MAX; m2[r][j] = -FLT_MAX; i1[r][j] = 0; }

    asm volatile("s_waitcnt vmcnt(0)" ::: "memory");
    __syncthreads();                   // B1: half-0 + wn2 + flagN=0 resident

    // ---- two-pass scan: 16 B-tiles per pass, fold carries across passes ----
    for (int p = 0; p < 2; ++p) {
        const int cbase = p * KHALF;
        #pragma unroll 2
        for (int t = 0; t < 16; ++t) {
            const int code_l = t * 16 + lm;            // slot within Wbuf
            const int code   = cbase + code_l;
            const float cinit = wn2_s[code];
            half8 bh[4];
            #pragma unroll
            for (int ks = 0; ks < 4; ++ks) {
                const int off = code_l * 256 + ((((ks << 2) + lg) ^ (code_l & 7)) << 4);
                bh[ks] = *(const half8*)(Wbuf + off);
            }
            f32x4 acc[2];
            #pragma unroll
            for (int r = 0; r < 2; ++r) acc[r] = (f32x4){cinit, cinit, cinit, cinit};
            #pragma unroll
            for (int ks = 0; ks < 4; ++ks) {
                #pragma unroll
                for (int r = 0; r < 2; ++r)
                    acc[r] = __builtin_amdgcn_mfma_f32_16x16x32_f16(ah[r][ks], bh[ks], acc[r], 0, 0, 0);
            }
            #pragma unroll
            for (int r = 0; r < 2; ++r) {
                #pragma unroll
                for (int j = 0; j < 4; ++j) {
                    const float a = acc[r][j];
                    m2[r][j] = __builtin_amdgcn_fmed3f(a, m1[r][j], m2[r][j]);
                    const bool gt = a > m1[r][j];
                    m1[r][j] = fmaxf(m1[r][j], a);
                    i1[r][j] = gt ? code : i1[r][j];
                }
            }
        }
        if (p == 0) {
            __syncthreads();           // all waves done reading half-0
            stage(1);                  // DMA half-1 over the same buffer
            asm volatile("s_waitcnt vmcnt(0)" ::: "memory");
            __syncthreads();           // half-1 resident
        }
    }

    // ---- reduce (m1, idx, m2) across the 16 col-lanes (wave-local) ----
    #pragma unroll
    for (int sft = 1; sft < 16; sft <<= 1) {
        #pragma unroll
        for (int r = 0; r < 2; ++r) {
            #pragma unroll
            for (int j = 0; j < 4; ++j) {
                float o1 = __shfl_xor(m1[r][j], sft);
                float o2 = __shfl_xor(m2[r][j], sft);
                int   oi = __shfl_xor(i1[r][j], sft);
                if (o1 > m1[r][j] || (o1 == m1[r][j] && oi < i1[r][j])) {
                    m2[r][j] = fmaxf(m1[r][j], o2);
                    m1[r][j] = o1;
                    i1[r][j] = oi;
                } else {
                    m2[r][j] = fmaxf(m2[r][j], o1);
                }
            }
        }
    }

    float psum = 0.f;
    if (lm == 0) {
        #pragma unroll
        for (int r = 0; r < 2; ++r) {
            #pragma unroll
            for (int j = 0; j < 4; ++j) {
                const int row = w * RPW + r * 16 + lg * 4 + j;   // C row = lg*4 + reg
                sIdx[row] = i1[r][j];
                psum += xn_s[row] - 2.f * m1[r][j];              // dist^2 = ||x||^2 - 2a
                if (m1[r][j] - m2[r][j] < TAU_A) {
                    int pos = atomicAdd(&flagN, 1);
                    flagList[pos] = row;
                }
            }
        }
    }
    __syncthreads();                   // B2: sIdx + worklist complete

    // ---- exact refinement, block-distributed over the worklist ----
    {
        const int nf = flagN;
        const int cg    = lane >> 3;           // code subgroup 0..7
        const int dbase = (lane & 7) * 16;     // 16-dim slice per lane
        for (int fi = w; fi < nf; fi += WAVES) {
            const int rr = flagList[fi];
            const float* xp = Z + (row0 + rr) * Dn + dbase;
            double xd[16];
            #pragma unroll
            for (int q = 0; q < 16; q += 4) {
                float4 v = *(const float4*)(xp + q);
                xd[q] = v.x; xd[q+1] = v.y; xd[q+2] = v.z; xd[q+3] = v.w;
            }
            double best = 1e300; int bi = 0;
            for (int cb = 0; cb < 64; ++cb) {
                const int c = cb * 8 + cg;
                const float* wp = W + (size_t)c * Dn + dbase;
                double s = 0.0;
                #pragma unroll
                for (int q = 0; q < 16; q += 4) {
                    float4 wv = *(const float4*)(wp + q);
                    s += xd[q]   * (double)wv.x;
                    s += xd[q+1] * (double)wv.y;
                    s += xd[q+2] * (double)wv.z;
                    s += xd[q+3] * (double)wv.w;
                }
                s += __shfl_xor(s, 1);
                s += __shfl_xor(s, 2);
                s += __shfl_xor(s, 4);         // all 8 lanes of group hold dot(c)
                const double sc = wn64[c] - 2.0 * s;   // dist^2 - ||x||^2 (exact)
                if (sc < best) { best = sc; bi = c; } // ascending c => min-idx tiebreak
            }
            #pragma unroll
            for (int sft = 8; sft < 64; sft <<= 1) {
                double ob = __shfl_xor(best, sft);
                int    ok = __shfl_xor(bi, sft);
                if (ob < best || (ob == best && ok < bi)) { best = ob; bi = ok; }
            }
            if (lane == 0) sIdx[rr] = bi;
        }
    }
    __syncthreads();                   // B3: refined sIdx visible

    // ---- epilogue: gather W[ind], store z_q_st, ind, diff ----
    #pragma unroll
    for (int it = 0; it < 16; ++it) {
        int f4i = lane + it * 64;              // 0..1023
        int rl  = f4i >> 5, cq = f4i & 31;     // 32 rows x 32 float4
        int ind = sIdx[w * RPW + rl];
        float4 wv = ((const float4*)(W + (size_t)ind * Dn))[cq];
        ((float4*)(out + (row0 + w * RPW + rl) * Dn))[cq] = wv;
    }
    if (lane < RPW)
        out[IND_OFF + row0 + w * RPW + lane] = (float)sIdx[w * RPW + lane];

    #pragma unroll
    for (int sft = 1; sft < 64; sft <<= 1) psum += __shfl_xor(psum, sft);
    if (lane == 0) wpart[w] = psum;
    __syncthreads();
    if (tid == 0) {
        double t = 0.0;
        #pragma unroll
        for (int i = 0; i < WAVES; ++i) t += (double)wpart[i];
        atomicAdd(diffsum, t);
    }
}

__global__ void diff_kernel(const double* __restrict__ diffsum, float* __restrict__ out) {
    if (threadIdx.x == 0 && blockIdx.x == 0) {
        // KLD_SCALE * (COMMITMENT_COST + 1) * mean = 12.5 * mean
        out[DIFF_OFF] = (float)(12.5 * diffsum[0] / (double)ZQ_SIZE);
    }
}

extern "C" void kernel_launch(void* const* d_in, const int* in_sizes, int n_in,
                              void* d_out, int out_size, void* d_ws, size_t ws_size,
                              hipStream_t stream) {
    (void)in_sizes; (void)n_in; (void)out_size; (void)ws_size;
    const float* Z = (const float*)d_in[0];
    const float* W = (const float*)d_in[1];
    float* out = (float*)d_out;
    // ws: [0,8) diffsum; [64,2112) wn2 f32[512]; [2112,6208) wn64 f64[512];
    //     [8192, +128KB) Wp fp16 swizzled
    double* diffsum = (double*)d_ws;
    float*  wn2  = (float*)((char*)d_ws + 64);
    double* wn64 = (double*)((char*)d_ws + 2112);
    unsigned short* Wp = (unsigned short*)((char*)d_ws + 8192);

    hipMemsetAsync(d_ws, 0, 16, stream);
    prep_kernel<<<32, 256, 0, stream>>>(W, Wp, wn2, wn64);
    vq_main<<<NBLK, 512, 0, stream>>>(Z, W, Wp, wn2, wn64, out, diffsum);
    diff_kernel<<<1, 64, 0, stream>>>(diffsum, out);
}